// Round 1
// baseline (9204.781 us; speedup 1.0000x reference)
//
#include <hip/hip_runtime.h>

#define Bb 32
#define Tt 512
#define Dd 256
#define Pp 512
#define Hh 512
#define G4 2048
#define TC 128   // time-chunk length (4 chunks)

__device__ __forceinline__ float sigmf(float x){ return 1.0f/(1.0f+__expf(-x)); }
__device__ __forceinline__ float tanhf_(float x){ return 1.0f - 2.0f/(__expf(2.0f*x)+1.0f); }

// out[m] = sum_k A[m,k]^2
__global__ void k_rowsq(const float* __restrict__ A, float* __restrict__ o, int M, int K){
  int m = blockIdx.x*blockDim.x + threadIdx.x;
  if (m >= M) return;
  const float4* a4 = (const float4*)(A + (size_t)m*K);
  float s = 0.f;
  for (int i = 0; i < K/4; ++i){ float4 v = a4[i]; s += v.x*v.x + v.y*v.y + v.z*v.z + v.w*v.w; }
  o[m] = s;
}

// out (N x M) = in (M x N)^T
__global__ void k_transpose(const float* __restrict__ in, float* __restrict__ out, int M, int N){
  __shared__ float tile[32][33];
  int bn = blockIdx.x * 32;
  int bm = blockIdx.y * 32;
  int tx = threadIdx.x, ty = threadIdx.y; // block (32,8)
  #pragma unroll
  for (int i = 0; i < 32; i += 8)
    tile[ty+i][tx] = in[(size_t)(bm+ty+i)*N + bn+tx];
  __syncthreads();
  #pragma unroll
  for (int i = 0; i < 32; i += 8)
    out[(size_t)(bn+ty+i)*M + bm+tx] = tile[tx][ty+i];
}

// bx[r] = dot(W_ih[r,:], b_lin) + b_ih[r] + b_hh[r]
__global__ void k_bx(const float* __restrict__ Wih, const float* __restrict__ blin,
                     const float* __restrict__ bih, const float* __restrict__ bhh,
                     float* __restrict__ bx){
  int r = blockIdx.x*blockDim.x + threadIdx.x; // 2048 threads
  const float4* w4 = (const float4*)(Wih + (size_t)r*Hh);
  const float4* b4 = (const float4*)blin;
  float s = 0.f;
  for (int i = 0; i < Hh/4; ++i){ float4 w=w4[i], b=b4[i]; s += w.x*b.x+w.y*b.y+w.z*b.z+w.w*b.w; }
  bx[r] = s + bih[r] + bhh[r];
}

// Wpack[k][j][g] = W_hh[g*512+j][k]  (gate-interleaved, float4 per (k,j))
__global__ void k_packWhh(const float* __restrict__ Whh, float4* __restrict__ Wp){
  int id = blockIdx.x*blockDim.x + threadIdx.x; // 512*512
  int k = id & (Hh-1);
  int j = id >> 9;
  float4 v;
  v.x = Whh[((size_t)(0*Hh+j))*Hh + k];
  v.y = Whh[((size_t)(1*Hh+j))*Hh + k];
  v.z = Whh[((size_t)(2*Hh+j))*Hh + k];
  v.w = Whh[((size_t)(3*Hh+j))*Hh + k];
  Wp[(size_t)k*Hh + j] = v;
}

// Generic tiled fp32 GEMM: C[M,N] = epi(A[M,K] @ B[K,N])
// EPI 0: none. EPI 1: exp(-max(rowAux[m]+colAux[n]-2*acc,0)). EPI 2: acc+colAux[n].
// REMAP: A-row (and rowAux) index m -> (m>>7)*Tt + t0 + (m&127); C stays dense.
template<int EPI, bool REMAP>
__global__ __launch_bounds__(256) void k_gemm(const float* __restrict__ A, const float* __restrict__ Bm,
                                              float* __restrict__ C, int M, int N, int K,
                                              const float* __restrict__ rowAux,
                                              const float* __restrict__ colAux, int t0)
{
  __shared__ float As[16][132];
  __shared__ float Bs[16][68];
  const int tid = threadIdx.x;
  const int bm = blockIdx.x * 128;
  const int bn = blockIdx.y * 64;
  const int tm = (tid & 15) * 8;
  const int tn = (tid >> 4) * 4;
  const int arow = tid >> 1;
  const int akq  = (tid & 1) * 8;
  const int brow = tid >> 4;
  const int bcol = (tid & 15) * 4;
  const int am = bm + arow;
  const size_t aRow = REMAP ? ((size_t)(am >> 7) * Tt + t0 + (am & 127)) : (size_t)am;
  float acc[8][4] = {};
  for (int k0 = 0; k0 < K; k0 += 16){
    float4 a0 = *(const float4*)&A[aRow*K + k0 + akq];
    float4 a1 = *(const float4*)&A[aRow*K + k0 + akq + 4];
    float4 bv = *(const float4*)&Bm[(size_t)(k0 + brow)*N + bn + bcol];
    As[akq+0][arow]=a0.x; As[akq+1][arow]=a0.y; As[akq+2][arow]=a0.z; As[akq+3][arow]=a0.w;
    As[akq+4][arow]=a1.x; As[akq+5][arow]=a1.y; As[akq+6][arow]=a1.z; As[akq+7][arow]=a1.w;
    *(float4*)&Bs[brow][bcol] = bv;
    __syncthreads();
    #pragma unroll
    for (int kk = 0; kk < 16; ++kk){
      float4 x0 = *(const float4*)&As[kk][tm];
      float4 x1 = *(const float4*)&As[kk][tm+4];
      float4 y  = *(const float4*)&Bs[kk][tn];
      float av[8] = {x0.x,x0.y,x0.z,x0.w,x1.x,x1.y,x1.z,x1.w};
      #pragma unroll
      for (int i=0;i<8;++i){
        float a = av[i];
        acc[i][0] += a*y.x; acc[i][1] += a*y.y; acc[i][2] += a*y.z; acc[i][3] += a*y.w;
      }
    }
    __syncthreads();
  }
  #pragma unroll
  for (int i=0;i<8;++i){
    int m = bm + tm + i;
    size_t mAux = REMAP ? ((size_t)(m >> 7) * Tt + t0 + (m & 127)) : (size_t)m;
    float4 o;
    float vv[4];
    #pragma unroll
    for (int j=0;j<4;++j){
      int n = bn + tn + j;
      float v = acc[i][j];
      if (EPI==1)      v = __expf(-fmaxf(rowAux[mAux] + colAux[n] - 2.f*v, 0.f));
      else if (EPI==2) v = v + colAux[n];
      vv[j] = v;
    }
    o.x=vv[0]; o.y=vv[1]; o.z=vv[2]; o.w=vv[3];
    *(float4*)&C[(size_t)m*N + bn + tn] = o;
  }
}

// One LSTM time step. 64 WGs x 1024 thr: WG owns 64 hidden units x 4 batches.
// Wp4: gate-interleaved W_hh^T, index (k*512 + j) -> float4 {i,f,g,o}.
// xs_chunk rows: (b*TC + tl) * 2048, gate layout [g*512 + j].
// h(t-1) is read from out[:, t-1, :]; h(t) written to out[:, t, :]; c persists in ws.
__global__ __launch_bounds__(1024) void k_lstm(const float4* __restrict__ Wp4,
                                               const float* __restrict__ xs,
                                               float* __restrict__ c,
                                               float* __restrict__ out,
                                               int t, int tl)
{
  __shared__ float hs[4][512];
  __shared__ float4 cpart[3][256];
  const int tid = threadIdx.x;
  const int j0 = (blockIdx.x & 7) * 64;
  const int b0 = (blockIdx.x >> 3) * 4;
  {
    int idx = tid * 2;
    int blh = idx >> 9;
    int k2  = idx & 511;
    if (t == 0){ hs[blh][k2] = 0.f; hs[blh][k2+1] = 0.f; }
    else {
      float2 v = *(const float2*)&out[(size_t)(b0+blh)*Tt*Hh + (size_t)(t-1)*Hh + k2];
      hs[blh][k2] = v.x; hs[blh][k2+1] = v.y;
    }
  }
  __syncthreads();
  const int jl = tid & 63;
  const int bl = (tid >> 6) & 3;
  const int kh = tid >> 8;       // k-split 0..3, 128 k each
  const int j  = j0 + jl;
  float4 acc = {0.f,0.f,0.f,0.f};
  const float4* wp = Wp4 + (size_t)(kh*128)*Hh + j;
  const float* hrow = &hs[bl][kh*128];
  #pragma unroll 8
  for (int kk = 0; kk < 128; ++kk){
    float4 w = wp[(size_t)kk*Hh];
    float hv = hrow[kk];
    acc.x += w.x*hv; acc.y += w.y*hv; acc.z += w.z*hv; acc.w += w.w*hv;
  }
  if (kh > 0) cpart[kh-1][(bl<<6)+jl] = acc;
  __syncthreads();
  if (kh == 0){
    float4 p0 = cpart[0][(bl<<6)+jl];
    float4 p1 = cpart[1][(bl<<6)+jl];
    float4 p2 = cpart[2][(bl<<6)+jl];
    acc.x += p0.x+p1.x+p2.x; acc.y += p0.y+p1.y+p2.y;
    acc.z += p0.z+p1.z+p2.z; acc.w += p0.w+p1.w+p2.w;
    const int b = b0 + bl;
    const size_t nrow = ((size_t)b*TC + tl)*G4;
    float gi = sigmf (acc.x + xs[nrow + 0*Hh + j]);
    float gf = sigmf (acc.y + xs[nrow + 1*Hh + j]);
    float gg = tanhf_(acc.z + xs[nrow + 2*Hh + j]);
    float go = sigmf (acc.w + xs[nrow + 3*Hh + j]);
    const int ci = b*Hh + j;
    float cn = gf*c[ci] + gi*gg;
    c[ci] = cn;
    out[(size_t)b*Tt*Hh + (size_t)t*Hh + j] = go * tanhf_(cn);
  }
}

extern "C" void kernel_launch(void* const* d_in, const int* in_sizes, int n_in,
                              void* d_out, int out_size, void* d_ws, size_t ws_size,
                              hipStream_t stream)
{
  const float* x    = (const float*)d_in[0];
  const float* prot = (const float*)d_in[1];
  const float* Wlin = (const float*)d_in[2];
  const float* blin = (const float*)d_in[3];
  const float* Wih  = (const float*)d_in[4];
  const float* Whh  = (const float*)d_in[5];
  const float* bih  = (const float*)d_in[6];
  const float* bhh  = (const float*)d_in[7];
  float* out = (float*)d_out;
  float* ws  = (float*)d_ws;

  size_t off = 0;
  auto alloc = [&](size_t n)->float*{ float* p = ws + off; off += (n + 15) & ~((size_t)15); return p; };
  float* x2    = alloc((size_t)Bb*Tt);        // 16384
  float* p2    = alloc(Pp);                   // 512
  float* pT    = alloc((size_t)Dd*Pp);        // 256x512
  float* bx    = alloc(G4);                   // 2048
  float* Wx    = alloc((size_t)G4*Pp);        // 2048x512
  float* WxT   = alloc((size_t)Pp*G4);        // 512x2048
  float* Wp    = alloc((size_t)Hh*G4);        // 512x512x4 gate-interleaved
  float* cbuf  = alloc((size_t)Bb*Hh);        // 32x512
  float* featsC= alloc((size_t)Bb*TC*Pp);     // 4096x512
  float* xsC   = alloc((size_t)Bb*TC*G4);     // 4096x2048
  // total ~14.6M floats ~ 58 MB (must be <= ws_size)

  // ---- setup (recomputed every call; deterministic) ----
  k_rowsq<<<dim3((Bb*Tt)/256), dim3(256), 0, stream>>>(x, x2, Bb*Tt, Dd);
  k_rowsq<<<dim3(Pp/256), dim3(256), 0, stream>>>(prot, p2, Pp, Dd);
  k_transpose<<<dim3(Dd/32, Pp/32), dim3(32,8), 0, stream>>>(prot, pT, Pp, Dd);
  k_bx<<<dim3(G4/256), dim3(256), 0, stream>>>(Wih, blin, bih, bhh, bx);
  // Wx[r,p] = sum_h W_ih[r,h] * W_lin[h,p]
  k_gemm<0,false><<<dim3(G4/128, Pp/64), dim3(256), 0, stream>>>(Wih, Wlin, Wx, G4, Pp, Hh, nullptr, nullptr, 0);
  k_transpose<<<dim3(Pp/32, G4/32), dim3(32,8), 0, stream>>>(Wx, WxT, G4, Pp);
  k_packWhh<<<dim3((Hh*Hh)/256), dim3(256), 0, stream>>>(Whh, (float4*)Wp);
  hipMemsetAsync(cbuf, 0, (size_t)Bb*Hh*sizeof(float), stream);

  // ---- main: 4 time-chunks of 128 steps ----
  for (int ch = 0; ch < Tt/TC; ++ch){
    int t0 = ch * TC;
    // feats chunk: rows m=(b*128+tl) <- x row (b*512 + t0 + tl)
    k_gemm<1,true><<<dim3((Bb*TC)/128, Pp/64), dim3(256), 0, stream>>>(
        x, pT, featsC, Bb*TC, Pp, Dd, x2, p2, t0);
    // xs chunk = featsC @ WxT + bx
    k_gemm<2,false><<<dim3((Bb*TC)/128, G4/64), dim3(256), 0, stream>>>(
        featsC, WxT, xsC, Bb*TC, G4, Pp, nullptr, bx, 0);
    for (int tl = 0; tl < TC; ++tl){
      k_lstm<<<dim3(64), dim3(1024), 0, stream>>>((const float4*)Wp, xsC, cbuf, out, t0 + tl, tl);
    }
  }
}

// Round 2
// 3712.684 us; speedup vs baseline: 2.4793x; 2.4793x over previous
//
#include <hip/hip_runtime.h>

#define Bb 32
#define Tt 512
#define Dd 256
#define Pp 512
#define Hh 512
#define G4 2048
#define TC 128   // time-chunk length (4 chunks)
#define NG 8     // batch groups (XCD-aligned via blockIdx%8)
#define WPG 16   // workgroups per group
#define NBG 4    // batches per group

__device__ __forceinline__ float sigmf(float x){ return 1.0f/(1.0f+__expf(-x)); }
__device__ __forceinline__ float tanhf_(float x){ return 1.0f - 2.0f/(__expf(2.0f*x)+1.0f); }

// out[m] = sum_k A[m,k]^2
__global__ void k_rowsq(const float* __restrict__ A, float* __restrict__ o, int M, int K){
  int m = blockIdx.x*blockDim.x + threadIdx.x;
  if (m >= M) return;
  const float4* a4 = (const float4*)(A + (size_t)m*K);
  float s = 0.f;
  for (int i = 0; i < K/4; ++i){ float4 v = a4[i]; s += v.x*v.x + v.y*v.y + v.z*v.z + v.w*v.w; }
  o[m] = s;
}

// out (N x M) = in (M x N)^T
__global__ void k_transpose(const float* __restrict__ in, float* __restrict__ out, int M, int N){
  __shared__ float tile[32][33];
  int bn = blockIdx.x * 32;
  int bm = blockIdx.y * 32;
  int tx = threadIdx.x, ty = threadIdx.y; // block (32,8)
  #pragma unroll
  for (int i = 0; i < 32; i += 8)
    tile[ty+i][tx] = in[(size_t)(bm+ty+i)*N + bn+tx];
  __syncthreads();
  #pragma unroll
  for (int i = 0; i < 32; i += 8)
    out[(size_t)(bn+ty+i)*M + bm+tx] = tile[tx][ty+i];
}

// bx[r] = dot(W_ih[r,:], b_lin) + b_ih[r] + b_hh[r]
__global__ void k_bx(const float* __restrict__ Wih, const float* __restrict__ blin,
                     const float* __restrict__ bih, const float* __restrict__ bhh,
                     float* __restrict__ bx){
  int r = blockIdx.x*blockDim.x + threadIdx.x; // 2048 threads
  const float4* w4 = (const float4*)(Wih + (size_t)r*Hh);
  const float4* b4 = (const float4*)blin;
  float s = 0.f;
  for (int i = 0; i < Hh/4; ++i){ float4 w=w4[i], b=b4[i]; s += w.x*b.x+w.y*b.y+w.z*b.z+w.w*b.w; }
  bx[r] = s + bih[r] + bhh[r];
}

// Generic tiled fp32 GEMM: C[M,N] = epi(A[M,K] @ B[K,N])
// EPI 0: none. EPI 1: exp(-max(rowAux[m]+colAux[n]-2*acc,0)). EPI 2: acc+colAux[n].
// REMAP: A-row (and rowAux) index m -> (m>>7)*Tt + t0 + (m&127); C stays dense.
template<int EPI, bool REMAP>
__global__ __launch_bounds__(256) void k_gemm(const float* __restrict__ A, const float* __restrict__ Bm,
                                              float* __restrict__ C, int M, int N, int K,
                                              const float* __restrict__ rowAux,
                                              const float* __restrict__ colAux, int t0)
{
  __shared__ float As[16][132];
  __shared__ float Bs[16][68];
  const int tid = threadIdx.x;
  const int bm = blockIdx.x * 128;
  const int bn = blockIdx.y * 64;
  const int tm = (tid & 15) * 8;
  const int tn = (tid >> 4) * 4;
  const int arow = tid >> 1;
  const int akq  = (tid & 1) * 8;
  const int brow = tid >> 4;
  const int bcol = (tid & 15) * 4;
  const int am = bm + arow;
  const size_t aRow = REMAP ? ((size_t)(am >> 7) * Tt + t0 + (am & 127)) : (size_t)am;
  float acc[8][4] = {};
  for (int k0 = 0; k0 < K; k0 += 16){
    float4 a0 = *(const float4*)&A[aRow*K + k0 + akq];
    float4 a1 = *(const float4*)&A[aRow*K + k0 + akq + 4];
    float4 bv = *(const float4*)&Bm[(size_t)(k0 + brow)*N + bn + bcol];
    As[akq+0][arow]=a0.x; As[akq+1][arow]=a0.y; As[akq+2][arow]=a0.z; As[akq+3][arow]=a0.w;
    As[akq+4][arow]=a1.x; As[akq+5][arow]=a1.y; As[akq+6][arow]=a1.z; As[akq+7][arow]=a1.w;
    *(float4*)&Bs[brow][bcol] = bv;
    __syncthreads();
    #pragma unroll
    for (int kk = 0; kk < 16; ++kk){
      float4 x0 = *(const float4*)&As[kk][tm];
      float4 x1 = *(const float4*)&As[kk][tm+4];
      float4 y  = *(const float4*)&Bs[kk][tn];
      float av[8] = {x0.x,x0.y,x0.z,x0.w,x1.x,x1.y,x1.z,x1.w};
      #pragma unroll
      for (int i=0;i<8;++i){
        float a = av[i];
        acc[i][0] += a*y.x; acc[i][1] += a*y.y; acc[i][2] += a*y.z; acc[i][3] += a*y.w;
      }
    }
    __syncthreads();
  }
  #pragma unroll
  for (int i=0;i<8;++i){
    int m = bm + tm + i;
    size_t mAux = REMAP ? ((size_t)(m >> 7) * Tt + t0 + (m & 127)) : (size_t)m;
    float4 o;
    float vv[4];
    #pragma unroll
    for (int j=0;j<4;++j){
      int n = bn + tn + j;
      float v = acc[i][j];
      if (EPI==1)      v = __expf(-fmaxf(rowAux[mAux] + colAux[n] - 2.f*v, 0.f));
      else if (EPI==2) v = v + colAux[n];
      vv[j] = v;
    }
    o.x=vv[0]; o.y=vv[1]; o.z=vv[2]; o.w=vv[3];
    *(float4*)&C[(size_t)m*N + bn + tn] = o;
  }
}

// Persistent LSTM over one time-chunk of TC steps.
// Grid: 128 WGs x 512 thr, cooperative. group gid = blockIdx%8 (4 batches),
// wg = blockIdx/8 owns 32 hidden units j in [wg*32, wg*32+32).
// Thread tid = ug*64 + ks*4 + gsel: W_hh rows (gsel*512 + wg*32+ug*4+r), r<4,
// k in [32ks,32ks+32) held in 128 VGPRs. h staged in XOR-swizzled LDS.
// Sync: per-group monotonic counter (release add / acquire spin, agent scope);
// h exchanged through `out` with relaxed agent-scope atomics.
__global__ __launch_bounds__(512, 2) void k_lstm_persist(
    const float* __restrict__ Whh, const float* __restrict__ xs,
    float* __restrict__ cbuf, float* __restrict__ out,
    unsigned* __restrict__ cnt, int t0)
{
  __shared__ float hbuf[NBG*Hh];   // 8 KB, swizzled
  const int tid  = threadIdx.x;
  const int gid  = blockIdx.x & 7;
  const int wg   = blockIdx.x >> 3;
  const int gsel = tid & 3;
  const int ks   = (tid >> 2) & 15;
  const int ug   = tid >> 6;
  const int jbase = wg*32 + ug*4;

  // ---- load W slice into registers (once per chunk) ----
  float W[4][32];
  #pragma unroll
  for (int r = 0; r < 4; ++r){
    const float* wrow = &Whh[(size_t)(gsel*Hh + jbase + r)*Hh + ks*32];
    #pragma unroll
    for (int c = 0; c < 8; ++c){
      float4 w = *(const float4*)&wrow[c*4];
      W[r][c*4+0]=w.x; W[r][c*4+1]=w.y; W[r][c*4+2]=w.z; W[r][c*4+3]=w.w;
    }
  }

  // this lane's post-reduction output identity
  const int rr = ks >> 2;
  const int bl = ks & 3;
  const int j  = jbase + rr;
  const int b  = gid*NBG + bl;
  float c_st = (t0 == 0) ? 0.f : cbuf[(size_t)b*Hh + j];

  // h-stage assignment
  const int sbl = tid >> 7;           // batch-local 0..3
  const int skb = (tid & 127) * 4;    // k base
  const int ssw = skb ^ (((skb >> 5) & 7) << 2);

  for (int tl = 0; tl < TC; ++tl){
    const int t = t0 + tl;
    // ---- stage h(t-1) into swizzled LDS ----
    float4 hv = {0.f,0.f,0.f,0.f};
    if (t > 0){
      const float* src = &out[((size_t)(gid*NBG + sbl)*Tt + (t-1))*Hh + skb];
      hv.x = __hip_atomic_load(src+0, __ATOMIC_RELAXED, __HIP_MEMORY_SCOPE_AGENT);
      hv.y = __hip_atomic_load(src+1, __ATOMIC_RELAXED, __HIP_MEMORY_SCOPE_AGENT);
      hv.z = __hip_atomic_load(src+2, __ATOMIC_RELAXED, __HIP_MEMORY_SCOPE_AGENT);
      hv.w = __hip_atomic_load(src+3, __ATOMIC_RELAXED, __HIP_MEMORY_SCOPE_AGENT);
    }
    *(float4*)&hbuf[sbl*Hh + ssw] = hv;
    __syncthreads();

    // ---- GEMV: acc[r][bl] += W[r][k] * h[bl][k] over this thread's k-slice ----
    float acc[4][4];
    #pragma unroll
    for (int r=0;r<4;++r){ acc[r][0]=0.f; acc[r][1]=0.f; acc[r][2]=0.f; acc[r][3]=0.f; }
    #pragma unroll
    for (int blq = 0; blq < 4; ++blq){
      const float* hb = &hbuf[blq*Hh + ks*32];
      #pragma unroll
      for (int c = 0; c < 8; ++c){
        float4 h4 = *(const float4*)&hb[(c*4) ^ ((ks & 7) << 2)];
        #pragma unroll
        for (int r = 0; r < 4; ++r){
          acc[r][blq] = fmaf(W[r][c*4+0], h4.x, acc[r][blq]);
          acc[r][blq] = fmaf(W[r][c*4+1], h4.y, acc[r][blq]);
          acc[r][blq] = fmaf(W[r][c*4+2], h4.z, acc[r][blq]);
          acc[r][blq] = fmaf(W[r][c*4+3], h4.w, acc[r][blq]);
        }
      }
    }

    // ---- in-wave reduction over ks (lane bits 2-5) ----
    #pragma unroll
    for (int m = 4; m <= 32; m <<= 1){
      #pragma unroll
      for (int r=0;r<4;++r){
        #pragma unroll
        for (int q=0;q<4;++q)
          acc[r][q] += __shfl_xor(acc[r][q], m, 64);
      }
    }
    // lane ks takes (r=ks>>2, q=ks&3)
    float g = acc[0][0];
    #pragma unroll
    for (int r=0;r<4;++r){
      #pragma unroll
      for (int q=0;q<4;++q)
        if (ks == r*4+q) g = acc[r][q];
    }

    // ---- add xs, collect 4 gates (consecutive lanes), update c,h ----
    g += xs[((size_t)b*TC + tl)*G4 + gsel*Hh + j];
    const int lbase = (tid & 63) & ~3;
    float gi = __shfl(g, lbase+0, 64);
    float gf = __shfl(g, lbase+1, 64);
    float gg = __shfl(g, lbase+2, 64);
    float go = __shfl(g, lbase+3, 64);
    gi = sigmf(gi); gf = sigmf(gf); gg = tanhf_(gg); go = sigmf(go);
    c_st = gf*c_st + gi*gg;
    float h = go * tanhf_(c_st);
    if (gsel == 0)
      __hip_atomic_store(&out[((size_t)b*Tt + t)*Hh + j], h,
                         __ATOMIC_RELAXED, __HIP_MEMORY_SCOPE_AGENT);
    __syncthreads();   // drains vmcnt: all this WG's h-stores complete

    // ---- group barrier: monotonic counter, target uses global step t ----
    if (tid == 0){
      __hip_atomic_fetch_add(&cnt[gid], 1u, __ATOMIC_RELEASE, __HIP_MEMORY_SCOPE_AGENT);
      const unsigned tgt = (unsigned)WPG * (unsigned)(t + 1);
      while (__hip_atomic_load(&cnt[gid], __ATOMIC_ACQUIRE, __HIP_MEMORY_SCOPE_AGENT) < tgt)
        __builtin_amdgcn_s_sleep(1);
    }
    __syncthreads();
  }
  if (gsel == 0) cbuf[(size_t)b*Hh + j] = c_st;
}

extern "C" void kernel_launch(void* const* d_in, const int* in_sizes, int n_in,
                              void* d_out, int out_size, void* d_ws, size_t ws_size,
                              hipStream_t stream)
{
  const float* x    = (const float*)d_in[0];
  const float* prot = (const float*)d_in[1];
  const float* Wlin = (const float*)d_in[2];
  const float* blin = (const float*)d_in[3];
  const float* Wih  = (const float*)d_in[4];
  const float* Whh  = (const float*)d_in[5];
  const float* bih  = (const float*)d_in[6];
  const float* bhh  = (const float*)d_in[7];
  float* out = (float*)d_out;
  float* ws  = (float*)d_ws;

  size_t off = 0;
  auto alloc = [&](size_t n)->float*{ float* p = ws + off; off += (n + 15) & ~((size_t)15); return p; };
  float* x2    = alloc((size_t)Bb*Tt);
  float* p2    = alloc(Pp);
  float* pT    = alloc((size_t)Dd*Pp);
  float* bx    = alloc(G4);
  float* Wx    = alloc((size_t)G4*Pp);
  float* WxT   = alloc((size_t)Pp*G4);
  float* cbuf  = alloc((size_t)Bb*Hh);
  float* featsC= alloc((size_t)Bb*TC*Pp);
  float* xsC   = alloc((size_t)Bb*TC*G4);
  unsigned* cnt = (unsigned*)alloc(16);
  // total ~13.6M floats ~ 55 MB

  // ---- setup ----
  k_rowsq<<<dim3((Bb*Tt)/256), dim3(256), 0, stream>>>(x, x2, Bb*Tt, Dd);
  k_rowsq<<<dim3(Pp/256), dim3(256), 0, stream>>>(prot, p2, Pp, Dd);
  k_transpose<<<dim3(Dd/32, Pp/32), dim3(32,8), 0, stream>>>(prot, pT, Pp, Dd);
  k_bx<<<dim3(G4/256), dim3(256), 0, stream>>>(Wih, blin, bih, bhh, bx);
  k_gemm<0,false><<<dim3(G4/128, Pp/64), dim3(256), 0, stream>>>(Wih, Wlin, Wx, G4, Pp, Hh, nullptr, nullptr, 0);
  k_transpose<<<dim3(Pp/32, G4/32), dim3(32,8), 0, stream>>>(Wx, WxT, G4, Pp);
  hipMemsetAsync(cnt, 0, NG*sizeof(unsigned), stream);

  // ---- main: 4 time-chunks of 128 steps ----
  for (int ch = 0; ch < Tt/TC; ++ch){
    int t0 = ch * TC;
    k_gemm<1,true><<<dim3((Bb*TC)/128, Pp/64), dim3(256), 0, stream>>>(
        x, pT, featsC, Bb*TC, Pp, Dd, x2, p2, t0);
    k_gemm<2,false><<<dim3((Bb*TC)/128, G4/64), dim3(256), 0, stream>>>(
        featsC, WxT, xsC, Bb*TC, G4, Pp, nullptr, bx, 0);
    void* args[] = { (void*)&Whh, (void*)&xsC, (void*)&cbuf, (void*)&out, (void*)&cnt, (void*)&t0 };
    hipLaunchCooperativeKernel((void*)k_lstm_persist, dim3(NG*WPG), dim3(512), args, 0, stream);
  }
}